// Round 19
// baseline (348.354 us; speedup 1.0000x reference)
//
#include <hip/hip_runtime.h>

#define BN_EPS 1e-5f

typedef _Float16 half_t;
typedef _Float16 half4 __attribute__((ext_vector_type(4)));
typedef _Float16 half8 __attribute__((ext_vector_type(8)));
typedef unsigned int u32;
typedef unsigned short u16;

__device__ __forceinline__ float norm_of(u32 w) {
    u16 hb = (u16)(w & 0x7fffu);
    return (float)__builtin_bit_cast(half_t, hb);
}

// ================= bucketed CSR build (bucket = dst >> 9, 512 nodes/bucket) ===========

#define EPB 4096

__global__ void k_bhist(const int* __restrict__ dst, int* __restrict__ countsT,
                        int nblk, int e) {
    __shared__ int h[256];
    h[threadIdx.x] = 0;
    __syncthreads();
    int base = blockIdx.x * EPB;
    int end = min(base + EPB, e);
    for (int i = base + threadIdx.x; i < end; i += 256)
        atomicAdd(&h[dst[i] >> 9], 1);
    __syncthreads();
    countsT[threadIdx.x * nblk + blockIdx.x] = h[threadIdx.x];
}

__global__ void k_colscan(int* __restrict__ countsT, int* __restrict__ colSum, int nblk) {
    __shared__ int lds[256];
    int t = threadIdx.x;
    int* col = countsT + (size_t)blockIdx.x * nblk;
    int carry = 0;
    for (int base = 0; base < nblk; base += 512) {
        int i0 = base + t * 2, i1 = i0 + 1;
        int v0 = (i0 < nblk) ? col[i0] : 0;
        int v1 = (i1 < nblk) ? col[i1] : 0;
        int s = v0 + v1;
        int val = s;
        lds[t] = val;
        __syncthreads();
        for (int off = 1; off < 256; off <<= 1) {
            int tmp = (t >= off) ? lds[t - off] : 0;
            __syncthreads();
            val += tmp;
            lds[t] = val;
            __syncthreads();
        }
        int run = carry + val - s;
        if (i0 < nblk) col[i0] = run;
        if (i1 < nblk) col[i1] = run + v0;
        carry += lds[255];
        __syncthreads();
    }
    if (t == 0) colSum[blockIdx.x] = carry;
}

__global__ void k_bscatter(const int* __restrict__ src, const int* __restrict__ dst,
                           const int* __restrict__ countsT, const int* __restrict__ colSum,
                           u32* __restrict__ rec, int nblk, int e) {
    __shared__ int lds[256];
    __shared__ int cur[256];
    int t = threadIdx.x;
    int s = colSum[t];
    int val = s;
    lds[t] = val;
    __syncthreads();
    for (int off = 1; off < 256; off <<= 1) {
        int tmp = (t >= off) ? lds[t - off] : 0;
        __syncthreads();
        val += tmp;
        lds[t] = val;
        __syncthreads();
    }
    int basev = val - s;
    cur[t] = countsT[t * nblk + blockIdx.x] + basev;
    __syncthreads();
    int base = blockIdx.x * EPB;
    int end = min(base + EPB, e);
    for (int i = base + t; i < end; i += 256) {
        int d = dst[i], sv = src[i];
        int pos = atomicAdd(&cur[d >> 9], 1);
        rec[pos] = ((u32)sv << 9) | (u32)(d & 511);
    }
}

__global__ void k_bbase(const int* __restrict__ colSum, int* __restrict__ bucketBase) {
    __shared__ int lds[256];
    int t = threadIdx.x;
    int s = colSum[t];
    int val = s;
    lds[t] = val;
    __syncthreads();
    for (int off = 1; off < 256; off <<= 1) {
        int tmp = (t >= off) ? lds[t - off] : 0;
        __syncthreads();
        val += tmp;
        lds[t] = val;
        __syncthreads();
    }
    bucketBase[t] = val - s;
    if (t == 255) bucketBase[256] = val;
}

__global__ void k_bmake1(const u32* __restrict__ rec, const int* __restrict__ bucketBase,
                         int* __restrict__ rowptr, float* __restrict__ dis,
                         float* __restrict__ dinv, int n) {
    __shared__ int h[512];
    __shared__ int ps[256];
    int t = threadIdx.x;
    h[t] = 0; h[t + 256] = 0;
    __syncthreads();
    int beg = bucketBase[blockIdx.x];
    int end = bucketBase[blockIdx.x + 1];
    for (int i = beg + t; i < end; i += 256)
        atomicAdd(&h[rec[i] & 511], 1);
    __syncthreads();
    int node0 = blockIdx.x << 9;
    int d0 = h[2 * t], d1 = h[2 * t + 1];
    int pair = d0 + d1;
    ps[t] = pair;
    __syncthreads();
    int val = pair;
    for (int off = 1; off < 256; off <<= 1) {
        int tmp = (t >= off) ? ps[t - off] : 0;
        __syncthreads();
        val += tmp;
        ps[t] = val;
        __syncthreads();
    }
    int excl0 = beg + val - pair;
    int nodeA = node0 + 2 * t, nodeB = nodeA + 1;
    if (nodeA <= n) rowptr[nodeA] = excl0;
    if (nodeB <= n) rowptr[nodeB] = excl0 + d0;
    if (nodeA < n) { float dd = (float)(d0 + 1); dis[nodeA] = rsqrtf(dd); dinv[nodeA] = 1.0f / dd; }
    if (nodeB < n) { float dd = (float)(d1 + 1); dis[nodeB] = rsqrtf(dd); dinv[nodeB] = 1.0f / dd; }
    if ((n & 511) == 0 && blockIdx.x == gridDim.x - 1 && t == 255) rowptr[n] = end;
}

__global__ void k_bfill(const u32* __restrict__ rec, const int* __restrict__ bucketBase,
                        const int* __restrict__ rowptr, const float* __restrict__ dis,
                        u32* __restrict__ csr, int n) {
    __shared__ int cur[512];
    __shared__ float disl[512];
    int t = threadIdx.x;
    int node0 = blockIdx.x << 9;
    for (int j = t; j < 512; j += 256) {
        int node = node0 + j;
        cur[j]  = (node < n) ? rowptr[node] : 0;
        disl[j] = (node < n) ? dis[node] : 0.0f;
    }
    __syncthreads();
    int beg = bucketBase[blockIdx.x];
    int end = bucketBase[blockIdx.x + 1];
    for (int i = beg + t; i < end; i += 256) {
        u32 r = rec[i];
        int dl = r & 511;
        int s = (int)(r >> 9);
        int pos = atomicAdd(&cur[dl], 1);
        half_t hh = (half_t)(dis[s] * disl[dl]);
        csr[pos] = ((u32)s << 15) | (u32)__builtin_bit_cast(u16, hh);
    }
}

// ================= X -> fp16 padded 24-wide =================

__global__ void k_x2h(const float* __restrict__ X, half_t* __restrict__ Xh, int n) {
    int i = blockIdx.x * blockDim.x + threadIdx.x;
    if (i >= n * 24) return;
    int node = i / 24, c = i % 24;
    Xh[i] = (c < 22) ? (half_t)X[(size_t)node * 22 + c] : (half_t)0.0f;
}

// ================= gather-aggregate (fp16 features, fp32 accumulate, fp16 out) ========

__global__ void k_gather22h(const half_t* __restrict__ Xh, const int* __restrict__ rowptr,
                            const u32* __restrict__ csr, const float* __restrict__ dinv,
                            half_t* __restrict__ out, int n) {
    int node = blockIdx.x * 4 + (threadIdx.x >> 6);
    if (node >= n) return;
    int lane = threadIdx.x & 63;
    int esub = lane >> 3;        // 0..7
    int sub  = lane & 7;         // 0..7
    bool act = sub < 6;
    const half4* X4 = (const half4*)Xh;   // 6 half4 per node
    int beg = rowptr[node], end = rowptr[node + 1];
    float4 a0 = make_float4(0, 0, 0, 0), a1 = a0;
    for (int e = beg; e < end; e += 16) {
        int i0 = e + esub, i1 = e + 8 + esub;
        u32 w0 = csr[min(i0, end - 1)];
        u32 w1 = csr[min(i1, end - 1)];
        if (act && i0 < end) {
            float nn = norm_of(w0);
            half4 h = X4[(size_t)(w0 >> 15) * 6 + sub];
            a0.x = fmaf((float)h.x, nn, a0.x); a0.y = fmaf((float)h.y, nn, a0.y);
            a0.z = fmaf((float)h.z, nn, a0.z); a0.w = fmaf((float)h.w, nn, a0.w);
        }
        if (act && i1 < end) {
            float nn = norm_of(w1);
            half4 h = X4[(size_t)(w1 >> 15) * 6 + sub];
            a1.x = fmaf((float)h.x, nn, a1.x); a1.y = fmaf((float)h.y, nn, a1.y);
            a1.z = fmaf((float)h.z, nn, a1.z); a1.w = fmaf((float)h.w, nn, a1.w);
        }
    }
    float4 a;
    a.x = a0.x + a1.x; a.y = a0.y + a1.y; a.z = a0.z + a1.z; a.w = a0.w + a1.w;
#pragma unroll
    for (int d = 8; d <= 32; d <<= 1) {
        a.x += __shfl_xor(a.x, d); a.y += __shfl_xor(a.y, d);
        a.z += __shfl_xor(a.z, d); a.w += __shfl_xor(a.w, d);
    }
    if (esub == 0 && act) {
        float di = dinv[node];
        half4 hs = X4[(size_t)node * 6 + sub];
        half4 r;
        r.x = (half_t)fmaf((float)hs.x, di, a.x);
        r.y = (half_t)fmaf((float)hs.y, di, a.y);
        r.z = (half_t)fmaf((float)hs.z, di, a.z);
        r.w = (half_t)fmaf((float)hs.w, di, a.w);
        ((half4*)out)[(size_t)node * 6 + sub] = r;
    }
}

// 64-wide: HALF-WAVE per node; lane = nodeSub(2) x esub(4) x sub(8); half8 loads
__global__ void k_gather64h(const half_t* __restrict__ H, const int* __restrict__ rowptr,
                            const u32* __restrict__ csr, const float* __restrict__ dinv,
                            half_t* __restrict__ out, int n) {
    int lane = threadIdx.x & 63;
    int nsub = lane >> 5;        // 0..1 (half-wave)
    int hl   = lane & 31;
    int esub = hl >> 3;          // 0..3
    int sub  = hl & 7;           // 0..7
    int node = blockIdx.x * 8 + (int)(threadIdx.x >> 6) * 2 + nsub;
    if (node >= n) return;
    const half8* H8 = (const half8*)H;    // 8 half8 per node
    int beg = rowptr[node], end = rowptr[node + 1];
    float a0[8], a1[8];
#pragma unroll
    for (int j = 0; j < 8; ++j) { a0[j] = 0.0f; a1[j] = 0.0f; }
    for (int e = beg; e < end; e += 8) {
        int i0 = e + esub, i1 = e + 4 + esub;
        u32 w0 = csr[min(i0, end - 1)];
        u32 w1 = csr[min(i1, end - 1)];
        if (i0 < end) {
            float nn = norm_of(w0);
            half8 h = H8[(size_t)(w0 >> 15) * 8 + sub];
#pragma unroll
            for (int j = 0; j < 8; ++j) a0[j] = fmaf((float)h[j], nn, a0[j]);
        }
        if (i1 < end) {
            float nn = norm_of(w1);
            half8 h = H8[(size_t)(w1 >> 15) * 8 + sub];
#pragma unroll
            for (int j = 0; j < 8; ++j) a1[j] = fmaf((float)h[j], nn, a1[j]);
        }
    }
    float acc[8];
#pragma unroll
    for (int j = 0; j < 8; ++j) acc[j] = a0[j] + a1[j];
#pragma unroll
    for (int d = 8; d <= 16; d <<= 1) {
#pragma unroll
        for (int j = 0; j < 8; ++j) acc[j] += __shfl_xor(acc[j], d);
    }
    if (esub == 0) {
        float di = dinv[node];
        half8 hs = H8[(size_t)node * 8 + sub];
        half8 r;
#pragma unroll
        for (int j = 0; j < 8; ++j) r[j] = (half_t)fmaf((float)hs[j], di, acc[j]);
        ((half8*)out)[(size_t)node * 8 + sub] = r;
    }
}

// ================= weight prep =================

__global__ void k_prep_all(const float* __restrict__ W1, const float* __restrict__ b1,
                           const float* __restrict__ g1, const float* __restrict__ be1,
                           const float* __restrict__ m1, const float* __restrict__ v1,
                           const float* __restrict__ W2, const float* __restrict__ b2,
                           const float* __restrict__ g2, const float* __restrict__ be2,
                           const float* __restrict__ m2, const float* __restrict__ v2,
                           const float* __restrict__ W3, const float* __restrict__ b3,
                           float* __restrict__ Wp1, float* __restrict__ C1,
                           float* __restrict__ Wp2, float* __restrict__ C2,
                           float* __restrict__ Wp3, float* __restrict__ C3) {
    int i = blockIdx.x * blockDim.x + threadIdx.x;
    if (i < 24 * 64) {
        int r = i / 64, c = i % 64;
        float A = g1[c] * rsqrtf(v1[c] + BN_EPS);
        Wp1[i] = (r < 22) ? W1[r * 64 + c] * A : 0.0f;
        if (i < 64) C1[i] = be1[i] + (b1[i] - m1[i]) * A;
    }
    int j = i - 24 * 64;
    if (j >= 0 && j < 64 * 64) {
        int c = j % 64;
        float A = g2[c] * rsqrtf(v2[c] + BN_EPS);
        Wp2[j] = W2[j] * A;
        if (j < 64) C2[j] = be2[j] + (b2[j] - m2[j]) * A;
    }
    int k = i - 24 * 64 - 64 * 64;
    if (k >= 0 && k < 64 * 128) {
        Wp3[k] = W3[k];
        if (k < 128) C3[k] = b3[k];
    }
}

// ================= GEMM (layers 1,2): fp16 in/out; wave-split columns =================

template <int FIN, int FOUT>
__global__ __launch_bounds__(256) void k_gemm2(const half_t* __restrict__ P,
                                               const float* __restrict__ Wp,
                                               const float* __restrict__ Cf,
                                               half_t* __restrict__ outp, int n) {
    constexpr int COLS = FOUT / 4;
    int lane = threadIdx.x & 63;
    int part = __builtin_amdgcn_readfirstlane(threadIdx.x >> 6);
    int node = blockIdx.x * 64 + lane;
    if (node >= n) return;

    half8 xr[FIN / 8];
    const half8* p8 = (const half8*)(P + (size_t)node * FIN);
#pragma unroll
    for (int i = 0; i < FIN / 8; ++i) xr[i] = p8[i];
    const half_t* x = (const half_t*)xr;

    const float* wq = Wp + part * COLS;
    const float* cq = Cf + part * COLS;

#pragma unroll 1
    for (int c0 = 0; c0 < COLS; c0 += 16) {
        float4 a0 = make_float4(0, 0, 0, 0), a1 = a0, a2 = a0, a3 = a0;
        const float* wbase = wq + c0;
#pragma unroll
        for (int k = 0; k < FIN; ++k) {
            float xv = (float)x[k];
            const float4* wr = (const float4*)(wbase + k * FOUT);
            float4 w0 = wr[0], w1 = wr[1], w2 = wr[2], w3 = wr[3];
            a0.x = fmaf(xv, w0.x, a0.x); a0.y = fmaf(xv, w0.y, a0.y);
            a0.z = fmaf(xv, w0.z, a0.z); a0.w = fmaf(xv, w0.w, a0.w);
            a1.x = fmaf(xv, w1.x, a1.x); a1.y = fmaf(xv, w1.y, a1.y);
            a1.z = fmaf(xv, w1.z, a1.z); a1.w = fmaf(xv, w1.w, a1.w);
            a2.x = fmaf(xv, w2.x, a2.x); a2.y = fmaf(xv, w2.y, a2.y);
            a2.z = fmaf(xv, w2.z, a2.z); a2.w = fmaf(xv, w2.w, a2.w);
            a3.x = fmaf(xv, w3.x, a3.x); a3.y = fmaf(xv, w3.y, a3.y);
            a3.z = fmaf(xv, w3.z, a3.z); a3.w = fmaf(xv, w3.w, a3.w);
        }
        const float4* c4 = (const float4*)(cq + c0);
        float4 cA = c4[0], cB = c4[1], cC = c4[2], cD = c4[3];
        half8 h0, h1;
        h0[0] = (half_t)fmaxf(a0.x + cA.x, 0.0f); h0[1] = (half_t)fmaxf(a0.y + cA.y, 0.0f);
        h0[2] = (half_t)fmaxf(a0.z + cA.z, 0.0f); h0[3] = (half_t)fmaxf(a0.w + cA.w, 0.0f);
        h0[4] = (half_t)fmaxf(a1.x + cB.x, 0.0f); h0[5] = (half_t)fmaxf(a1.y + cB.y, 0.0f);
        h0[6] = (half_t)fmaxf(a1.z + cB.z, 0.0f); h0[7] = (half_t)fmaxf(a1.w + cB.w, 0.0f);
        h1[0] = (half_t)fmaxf(a2.x + cC.x, 0.0f); h1[1] = (half_t)fmaxf(a2.y + cC.y, 0.0f);
        h1[2] = (half_t)fmaxf(a2.z + cC.z, 0.0f); h1[3] = (half_t)fmaxf(a2.w + cC.w, 0.0f);
        h1[4] = (half_t)fmaxf(a3.x + cD.x, 0.0f); h1[5] = (half_t)fmaxf(a3.y + cD.y, 0.0f);
        h1[6] = (half_t)fmaxf(a3.z + cD.z, 0.0f); h1[7] = (half_t)fmaxf(a3.w + cD.w, 0.0f);
        half8* oh = (half8*)(outp + (size_t)node * FOUT + part * COLS + c0);
        oh[0] = h0;
        oh[1] = h1;
    }
}

// ================= FUSED gemm3 (64->128) + pool via in-wave segmented reduction =======
// No LDS, no barrier. lane = node; after GEMM each lane holds 16 ReLU'd cols per chunk.
// batch sorted -> wave spans few graphs; per graph: masked butterfly + lane-0 atomics.

__global__ __launch_bounds__(256) void k_gemm3pool(const half_t* __restrict__ P,
                                                   const float* __restrict__ Wp,
                                                   const float* __restrict__ Cf,
                                                   const int* __restrict__ batch,
                                                   float* __restrict__ sums, int n) {
    constexpr int FIN = 64, FOUT = 128, COLS = 32;
    int lane = threadIdx.x & 63;
    int part = __builtin_amdgcn_readfirstlane(threadIdx.x >> 6);
    int node = blockIdx.x * 64 + lane;
    bool valid = node < n;
    int myB = valid ? batch[node] : -1;

    // graph id range within this 64-node window (batch sorted -> small range)
    int gmin = valid ? myB : 0x7fffffff;
    int gmax = valid ? myB : -1;
#pragma unroll
    for (int d = 1; d < 64; d <<= 1) {
        gmin = min(gmin, __shfl_xor(gmin, d));
        gmax = max(gmax, __shfl_xor(gmax, d));
    }

    half8 xr[FIN / 8];
    if (valid) {
        const half8* p8 = (const half8*)(P + (size_t)node * FIN);
#pragma unroll
        for (int i = 0; i < FIN / 8; ++i) xr[i] = p8[i];
    } else {
#pragma unroll
        for (int i = 0; i < FIN / 8; ++i) xr[i] = half8{};
    }
    const half_t* x = (const half_t*)xr;
    const float* wq = Wp + part * COLS;
    const float* cq = Cf + part * COLS;

#pragma unroll 1
    for (int c0 = 0; c0 < COLS; c0 += 16) {
        float4 a0 = make_float4(0, 0, 0, 0), a1 = a0, a2 = a0, a3 = a0;
        const float* wbase = wq + c0;
#pragma unroll
        for (int k = 0; k < FIN; ++k) {
            float xv = (float)x[k];
            const float4* wr = (const float4*)(wbase + k * FOUT);
            float4 w0 = wr[0], w1 = wr[1], w2 = wr[2], w3 = wr[3];
            a0.x = fmaf(xv, w0.x, a0.x); a0.y = fmaf(xv, w0.y, a0.y);
            a0.z = fmaf(xv, w0.z, a0.z); a0.w = fmaf(xv, w0.w, a0.w);
            a1.x = fmaf(xv, w1.x, a1.x); a1.y = fmaf(xv, w1.y, a1.y);
            a1.z = fmaf(xv, w1.z, a1.z); a1.w = fmaf(xv, w1.w, a1.w);
            a2.x = fmaf(xv, w2.x, a2.x); a2.y = fmaf(xv, w2.y, a2.y);
            a2.z = fmaf(xv, w2.z, a2.z); a2.w = fmaf(xv, w2.w, a2.w);
            a3.x = fmaf(xv, w3.x, a3.x); a3.y = fmaf(xv, w3.y, a3.y);
            a3.z = fmaf(xv, w3.z, a3.z); a3.w = fmaf(xv, w3.w, a3.w);
        }
        const float4* c4 = (const float4*)(cq + c0);
        float4 cA = c4[0], cB = c4[1], cC = c4[2], cD = c4[3];
        float r[16];
        r[0]  = fmaxf(a0.x + cA.x, 0.0f); r[1]  = fmaxf(a0.y + cA.y, 0.0f);
        r[2]  = fmaxf(a0.z + cA.z, 0.0f); r[3]  = fmaxf(a0.w + cA.w, 0.0f);
        r[4]  = fmaxf(a1.x + cB.x, 0.0f); r[5]  = fmaxf(a1.y + cB.y, 0.0f);
        r[6]  = fmaxf(a1.z + cB.z, 0.0f); r[7]  = fmaxf(a1.w + cB.w, 0.0f);
        r[8]  = fmaxf(a2.x + cC.x, 0.0f); r[9]  = fmaxf(a2.y + cC.y, 0.0f);
        r[10] = fmaxf(a2.z + cC.z, 0.0f); r[11] = fmaxf(a2.w + cC.w, 0.0f);
        r[12] = fmaxf(a3.x + cD.x, 0.0f); r[13] = fmaxf(a3.y + cD.y, 0.0f);
        r[14] = fmaxf(a3.z + cD.z, 0.0f); r[15] = fmaxf(a3.w + cD.w, 0.0f);

        for (int g = gmin; g <= gmax; ++g) {
            bool m = valid && (myB == g);
            float t[16];
#pragma unroll
            for (int j = 0; j < 16; ++j) t[j] = m ? r[j] : 0.0f;
#pragma unroll
            for (int d = 1; d < 64; d <<= 1) {
#pragma unroll
                for (int j = 0; j < 16; ++j) t[j] += __shfl_xor(t[j], d);
            }
            if (lane == 0) {
                float* sp = sums + (size_t)g * 128 + part * COLS + c0;
#pragma unroll
                for (int j = 0; j < 16; ++j) atomicAdd(&sp[j], t[j]);
            }
        }
    }
}

__global__ void k_pool_div(const float* __restrict__ sums, const int* __restrict__ batch,
                           float* __restrict__ out, int n, int nB) {
    int i = blockIdx.x * blockDim.x + threadIdx.x;
    if (i >= nB * 128) return;
    int b = i >> 7;
    int lo = 0, hi = n;
    while (lo < hi) { int mid = (lo + hi) >> 1; if (batch[mid] < b) lo = mid + 1; else hi = mid; }
    int start = lo;
    lo = 0; hi = n;
    while (lo < hi) { int mid = (lo + hi) >> 1; if (batch[mid] < b + 1) lo = mid + 1; else hi = mid; }
    float cnt = (float)(lo - start);
    out[i] = sums[i] / fmaxf(cnt, 1.0f);
}

// ================= launch =================

extern "C" void kernel_launch(void* const* d_in, const int* in_sizes, int n_in,
                              void* d_out, int out_size, void* d_ws, size_t ws_size,
                              hipStream_t stream) {
    const float* x   = (const float*)d_in[0];
    const int*   ei  = (const int*)d_in[1];
    const int*   bat = (const int*)d_in[2];
    const float* W1  = (const float*)d_in[3];
    const float* b1  = (const float*)d_in[4];
    const float* W2  = (const float*)d_in[5];
    const float* b2  = (const float*)d_in[6];
    const float* W3  = (const float*)d_in[7];
    const float* b3  = (const float*)d_in[8];
    const float* g1  = (const float*)d_in[9];
    const float* be1 = (const float*)d_in[10];
    const float* m1  = (const float*)d_in[11];
    const float* v1  = (const float*)d_in[12];
    const float* g2  = (const float*)d_in[13];
    const float* be2 = (const float*)d_in[14];
    const float* m2  = (const float*)d_in[15];
    const float* v2  = (const float*)d_in[16];

    const int N = in_sizes[0] / 22;
    const int E = in_sizes[1] / 2;
    const int B = out_size / 128;
    const int* src = ei;
    const int* dst = ei + E;

    const int nblk = (E + EPB - 1) / EPB;
    const int NBKT = (N + 511) >> 9;

    size_t off = 0;
    char* base = (char*)d_ws;
    auto alloc = [&](size_t bytes) -> void* {
        void* p = base + off;
        off = (off + bytes + 255) & ~(size_t)255;
        return p;
    };
    int*    rowptr = (int*)alloc((size_t)(N + 1) * 4);
    int*    countsT = (int*)alloc((size_t)nblk * 256 * 4);
    int*    colSum = (int*)alloc(256 * 4);
    int*    bucketBase = (int*)alloc(257 * 4);
    u32*    rec    = (u32*)alloc((size_t)E * 4);
    float*  dis    = (float*)alloc((size_t)N * 4);
    float*  dinv   = (float*)alloc((size_t)N * 4);
    u32*    csr    = (u32*)alloc((size_t)E * 4);
    half_t* Xh     = (half_t*)alloc((size_t)N * 24 * 2);
    half_t* Hh1    = (half_t*)alloc((size_t)N * 64 * 2);
    half_t* Hh2    = (half_t*)alloc((size_t)N * 64 * 2);
    half_t* aggH   = (half_t*)alloc((size_t)N * 64 * 2);
    float*  sums   = (float*)alloc((size_t)B * 128 * 4);
    float*  Wp1    = (float*)alloc(24 * 64 * 4);
    float*  Wp2    = (float*)alloc(64 * 64 * 4);
    float*  Wp3    = (float*)alloc(64 * 128 * 4);
    float*  C1     = (float*)alloc(64 * 4);
    float*  C2     = (float*)alloc(64 * 4);
    float*  C3     = (float*)alloc(128 * 4);

    const int T = 256;
    auto blk = [](long long n, int t) { return (int)((n + t - 1) / t); };

    // ---- weight prep ----
    k_prep_all<<<blk(24 * 64 + 64 * 64 + 64 * 128, T), T, 0, stream>>>(
        W1, b1, g1, be1, m1, v1, W2, b2, g2, be2, m2, v2, W3, b3,
        Wp1, C1, Wp2, C2, Wp3, C3);

    // ---- bucketed CSR build ----
    k_bhist<<<nblk, T, 0, stream>>>(dst, countsT, nblk, E);
    k_colscan<<<256, T, 0, stream>>>(countsT, colSum, nblk);
    k_bscatter<<<nblk, T, 0, stream>>>(src, dst, countsT, colSum, rec, nblk, E);
    k_bbase<<<1, 256, 0, stream>>>(colSum, bucketBase);
    k_bmake1<<<NBKT, T, 0, stream>>>(rec, bucketBase, rowptr, dis, dinv, N);
    k_bfill<<<NBKT, T, 0, stream>>>(rec, bucketBase, rowptr, dis, csr, N);

    // ---- X -> fp16 (padded 24) ----
    k_x2h<<<blk((long long)N * 24, T), T, 0, stream>>>(x, Xh, N);

    // ---- layer 1 ----
    k_gather22h<<<blk(N, 4), T, 0, stream>>>(Xh, rowptr, csr, dinv, aggH, N);
    k_gemm2<24, 64><<<blk(N, 64), T, 0, stream>>>(aggH, Wp1, C1, Hh1, N);

    // ---- layer 2 ----
    k_gather64h<<<blk(N, 8), T, 0, stream>>>(Hh1, rowptr, csr, dinv, aggH, N);
    k_gemm2<64, 64><<<blk(N, 64), T, 0, stream>>>(aggH, Wp2, C2, Hh2, N);

    // ---- layer 3 fused with pool-sum (in-wave segmented reduction) ----
    k_gather64h<<<blk(N, 8), T, 0, stream>>>(Hh2, rowptr, csr, dinv, aggH, N);
    hipMemsetAsync(sums, 0, (size_t)B * 128 * sizeof(float), stream);
    k_gemm3pool<<<blk(N, 64), T, 0, stream>>>(aggH, Wp3, C3, bat, sums, N);

    // ---- divide by counts ----
    k_pool_div<<<blk(B * 128, T), T, 0, stream>>>(sums, bat, (float*)d_out, N, B);
}

// Round 20
// 341.328 us; speedup vs baseline: 1.0206x; 1.0206x over previous
//
#include <hip/hip_runtime.h>

#define BN_EPS 1e-5f

typedef _Float16 half_t;
typedef _Float16 half4 __attribute__((ext_vector_type(4)));
typedef _Float16 half8 __attribute__((ext_vector_type(8)));
typedef unsigned int u32;
typedef unsigned short u16;

__device__ __forceinline__ float norm_of(u32 w) {
    u16 hb = (u16)(w & 0x7fffu);
    return (float)__builtin_bit_cast(half_t, hb);
}

// ================= bucketed CSR build (bucket = dst >> 9, 512 nodes/bucket) ===========

#define EPB 4096

__global__ void k_bhist(const int* __restrict__ dst, int* __restrict__ countsT,
                        int nblk, int e) {
    __shared__ int h[256];
    h[threadIdx.x] = 0;
    __syncthreads();
    int base = blockIdx.x * EPB;
    int end = min(base + EPB, e);
    for (int i = base + threadIdx.x; i < end; i += 256)
        atomicAdd(&h[dst[i] >> 9], 1);
    __syncthreads();
    countsT[threadIdx.x * nblk + blockIdx.x] = h[threadIdx.x];
}

__global__ void k_colscan(int* __restrict__ countsT, int* __restrict__ colSum, int nblk) {
    __shared__ int lds[256];
    int t = threadIdx.x;
    int* col = countsT + (size_t)blockIdx.x * nblk;
    int carry = 0;
    for (int base = 0; base < nblk; base += 512) {
        int i0 = base + t * 2, i1 = i0 + 1;
        int v0 = (i0 < nblk) ? col[i0] : 0;
        int v1 = (i1 < nblk) ? col[i1] : 0;
        int s = v0 + v1;
        int val = s;
        lds[t] = val;
        __syncthreads();
        for (int off = 1; off < 256; off <<= 1) {
            int tmp = (t >= off) ? lds[t - off] : 0;
            __syncthreads();
            val += tmp;
            lds[t] = val;
            __syncthreads();
        }
        int run = carry + val - s;
        if (i0 < nblk) col[i0] = run;
        if (i1 < nblk) col[i1] = run + v0;
        carry += lds[255];
        __syncthreads();
    }
    if (t == 0) colSum[blockIdx.x] = carry;
}

__global__ void k_bscatter(const int* __restrict__ src, const int* __restrict__ dst,
                           const int* __restrict__ countsT, const int* __restrict__ colSum,
                           u32* __restrict__ rec, int nblk, int e) {
    __shared__ int lds[256];
    __shared__ int cur[256];
    int t = threadIdx.x;
    int s = colSum[t];
    int val = s;
    lds[t] = val;
    __syncthreads();
    for (int off = 1; off < 256; off <<= 1) {
        int tmp = (t >= off) ? lds[t - off] : 0;
        __syncthreads();
        val += tmp;
        lds[t] = val;
        __syncthreads();
    }
    int basev = val - s;
    cur[t] = countsT[t * nblk + blockIdx.x] + basev;
    __syncthreads();
    int base = blockIdx.x * EPB;
    int end = min(base + EPB, e);
    for (int i = base + t; i < end; i += 256) {
        int d = dst[i], sv = src[i];
        int pos = atomicAdd(&cur[d >> 9], 1);
        rec[pos] = ((u32)sv << 9) | (u32)(d & 511);
    }
}

__global__ void k_bbase(const int* __restrict__ colSum, int* __restrict__ bucketBase) {
    __shared__ int lds[256];
    int t = threadIdx.x;
    int s = colSum[t];
    int val = s;
    lds[t] = val;
    __syncthreads();
    for (int off = 1; off < 256; off <<= 1) {
        int tmp = (t >= off) ? lds[t - off] : 0;
        __syncthreads();
        val += tmp;
        lds[t] = val;
        __syncthreads();
    }
    bucketBase[t] = val - s;
    if (t == 255) bucketBase[256] = val;
}

__global__ void k_bmake1(const u32* __restrict__ rec, const int* __restrict__ bucketBase,
                         int* __restrict__ rowptr, float* __restrict__ dis,
                         float* __restrict__ dinv, int n) {
    __shared__ int h[512];
    __shared__ int ps[256];
    int t = threadIdx.x;
    h[t] = 0; h[t + 256] = 0;
    __syncthreads();
    int beg = bucketBase[blockIdx.x];
    int end = bucketBase[blockIdx.x + 1];
    for (int i = beg + t; i < end; i += 256)
        atomicAdd(&h[rec[i] & 511], 1);
    __syncthreads();
    int node0 = blockIdx.x << 9;
    int d0 = h[2 * t], d1 = h[2 * t + 1];
    int pair = d0 + d1;
    ps[t] = pair;
    __syncthreads();
    int val = pair;
    for (int off = 1; off < 256; off <<= 1) {
        int tmp = (t >= off) ? ps[t - off] : 0;
        __syncthreads();
        val += tmp;
        ps[t] = val;
        __syncthreads();
    }
    int excl0 = beg + val - pair;
    int nodeA = node0 + 2 * t, nodeB = nodeA + 1;
    if (nodeA <= n) rowptr[nodeA] = excl0;
    if (nodeB <= n) rowptr[nodeB] = excl0 + d0;
    if (nodeA < n) { float dd = (float)(d0 + 1); dis[nodeA] = rsqrtf(dd); dinv[nodeA] = 1.0f / dd; }
    if (nodeB < n) { float dd = (float)(d1 + 1); dis[nodeB] = rsqrtf(dd); dinv[nodeB] = 1.0f / dd; }
    if ((n & 511) == 0 && blockIdx.x == gridDim.x - 1 && t == 255) rowptr[n] = end;
}

__global__ void k_bfill(const u32* __restrict__ rec, const int* __restrict__ bucketBase,
                        const int* __restrict__ rowptr, const float* __restrict__ dis,
                        u32* __restrict__ csr, int n) {
    __shared__ int cur[512];
    __shared__ float disl[512];
    int t = threadIdx.x;
    int node0 = blockIdx.x << 9;
    for (int j = t; j < 512; j += 256) {
        int node = node0 + j;
        cur[j]  = (node < n) ? rowptr[node] : 0;
        disl[j] = (node < n) ? dis[node] : 0.0f;
    }
    __syncthreads();
    int beg = bucketBase[blockIdx.x];
    int end = bucketBase[blockIdx.x + 1];
    for (int i = beg + t; i < end; i += 256) {
        u32 r = rec[i];
        int dl = r & 511;
        int s = (int)(r >> 9);
        int pos = atomicAdd(&cur[dl], 1);
        half_t hh = (half_t)(dis[s] * disl[dl]);
        csr[pos] = ((u32)s << 15) | (u32)__builtin_bit_cast(u16, hh);
    }
}

// ================= X -> fp16 padded 24-wide =================

__global__ void k_x2h(const float* __restrict__ X, half_t* __restrict__ Xh, int n) {
    int i = blockIdx.x * blockDim.x + threadIdx.x;
    if (i >= n * 24) return;
    int node = i / 24, c = i % 24;
    Xh[i] = (c < 22) ? (half_t)X[(size_t)node * 22 + c] : (half_t)0.0f;
}

// ================= gather-aggregate (fp16 features, fp32 accumulate, fp16 out) ========

__global__ void k_gather22h(const half_t* __restrict__ Xh, const int* __restrict__ rowptr,
                            const u32* __restrict__ csr, const float* __restrict__ dinv,
                            half_t* __restrict__ out, int n) {
    int node = blockIdx.x * 4 + (threadIdx.x >> 6);
    if (node >= n) return;
    int lane = threadIdx.x & 63;
    int esub = lane >> 3;        // 0..7
    int sub  = lane & 7;         // 0..7
    bool act = sub < 6;
    const half4* X4 = (const half4*)Xh;   // 6 half4 per node
    int beg = rowptr[node], end = rowptr[node + 1];
    float4 a0 = make_float4(0, 0, 0, 0), a1 = a0;
    for (int e = beg; e < end; e += 16) {
        int i0 = e + esub, i1 = e + 8 + esub;
        u32 w0 = csr[min(i0, end - 1)];
        u32 w1 = csr[min(i1, end - 1)];
        if (act && i0 < end) {
            float nn = norm_of(w0);
            half4 h = X4[(size_t)(w0 >> 15) * 6 + sub];
            a0.x = fmaf((float)h.x, nn, a0.x); a0.y = fmaf((float)h.y, nn, a0.y);
            a0.z = fmaf((float)h.z, nn, a0.z); a0.w = fmaf((float)h.w, nn, a0.w);
        }
        if (act && i1 < end) {
            float nn = norm_of(w1);
            half4 h = X4[(size_t)(w1 >> 15) * 6 + sub];
            a1.x = fmaf((float)h.x, nn, a1.x); a1.y = fmaf((float)h.y, nn, a1.y);
            a1.z = fmaf((float)h.z, nn, a1.z); a1.w = fmaf((float)h.w, nn, a1.w);
        }
    }
    float4 a;
    a.x = a0.x + a1.x; a.y = a0.y + a1.y; a.z = a0.z + a1.z; a.w = a0.w + a1.w;
#pragma unroll
    for (int d = 8; d <= 32; d <<= 1) {
        a.x += __shfl_xor(a.x, d); a.y += __shfl_xor(a.y, d);
        a.z += __shfl_xor(a.z, d); a.w += __shfl_xor(a.w, d);
    }
    if (esub == 0 && act) {
        float di = dinv[node];
        half4 hs = X4[(size_t)node * 6 + sub];
        half4 r;
        r.x = (half_t)fmaf((float)hs.x, di, a.x);
        r.y = (half_t)fmaf((float)hs.y, di, a.y);
        r.z = (half_t)fmaf((float)hs.z, di, a.z);
        r.w = (half_t)fmaf((float)hs.w, di, a.w);
        ((half4*)out)[(size_t)node * 6 + sub] = r;
    }
}

// 64-wide: HALF-WAVE per node; lane = nodeSub(2) x esub(4) x sub(8); half8 loads
__global__ void k_gather64h(const half_t* __restrict__ H, const int* __restrict__ rowptr,
                            const u32* __restrict__ csr, const float* __restrict__ dinv,
                            half_t* __restrict__ out, int n) {
    int lane = threadIdx.x & 63;
    int nsub = lane >> 5;        // 0..1 (half-wave)
    int hl   = lane & 31;
    int esub = hl >> 3;          // 0..3
    int sub  = hl & 7;           // 0..7
    int node = blockIdx.x * 8 + (int)(threadIdx.x >> 6) * 2 + nsub;
    if (node >= n) return;
    const half8* H8 = (const half8*)H;    // 8 half8 per node
    int beg = rowptr[node], end = rowptr[node + 1];
    float a0[8], a1[8];
#pragma unroll
    for (int j = 0; j < 8; ++j) { a0[j] = 0.0f; a1[j] = 0.0f; }
    for (int e = beg; e < end; e += 8) {
        int i0 = e + esub, i1 = e + 4 + esub;
        u32 w0 = csr[min(i0, end - 1)];
        u32 w1 = csr[min(i1, end - 1)];
        if (i0 < end) {
            float nn = norm_of(w0);
            half8 h = H8[(size_t)(w0 >> 15) * 8 + sub];
#pragma unroll
            for (int j = 0; j < 8; ++j) a0[j] = fmaf((float)h[j], nn, a0[j]);
        }
        if (i1 < end) {
            float nn = norm_of(w1);
            half8 h = H8[(size_t)(w1 >> 15) * 8 + sub];
#pragma unroll
            for (int j = 0; j < 8; ++j) a1[j] = fmaf((float)h[j], nn, a1[j]);
        }
    }
    float acc[8];
#pragma unroll
    for (int j = 0; j < 8; ++j) acc[j] = a0[j] + a1[j];
#pragma unroll
    for (int d = 8; d <= 16; d <<= 1) {
#pragma unroll
        for (int j = 0; j < 8; ++j) acc[j] += __shfl_xor(acc[j], d);
    }
    if (esub == 0) {
        float di = dinv[node];
        half8 hs = H8[(size_t)node * 8 + sub];
        half8 r;
#pragma unroll
        for (int j = 0; j < 8; ++j) r[j] = (half_t)fmaf((float)hs[j], di, acc[j]);
        ((half8*)out)[(size_t)node * 8 + sub] = r;
    }
}

// ================= weight prep =================

__global__ void k_prep_all(const float* __restrict__ W1, const float* __restrict__ b1,
                           const float* __restrict__ g1, const float* __restrict__ be1,
                           const float* __restrict__ m1, const float* __restrict__ v1,
                           const float* __restrict__ W2, const float* __restrict__ b2,
                           const float* __restrict__ g2, const float* __restrict__ be2,
                           const float* __restrict__ m2, const float* __restrict__ v2,
                           const float* __restrict__ W3, const float* __restrict__ b3,
                           float* __restrict__ Wp1, float* __restrict__ C1,
                           float* __restrict__ Wp2, float* __restrict__ C2,
                           float* __restrict__ Wp3, float* __restrict__ C3) {
    int i = blockIdx.x * blockDim.x + threadIdx.x;
    if (i < 24 * 64) {
        int r = i / 64, c = i % 64;
        float A = g1[c] * rsqrtf(v1[c] + BN_EPS);
        Wp1[i] = (r < 22) ? W1[r * 64 + c] * A : 0.0f;
        if (i < 64) C1[i] = be1[i] + (b1[i] - m1[i]) * A;
    }
    int j = i - 24 * 64;
    if (j >= 0 && j < 64 * 64) {
        int c = j % 64;
        float A = g2[c] * rsqrtf(v2[c] + BN_EPS);
        Wp2[j] = W2[j] * A;
        if (j < 64) C2[j] = be2[j] + (b2[j] - m2[j]) * A;
    }
    int k = i - 24 * 64 - 64 * 64;
    if (k >= 0 && k < 64 * 128) {
        Wp3[k] = W3[k];
        if (k < 128) C3[k] = b3[k];
    }
}

// ================= GEMM: fp16 in/out; wave-split columns =================

template <int FIN, int FOUT>
__global__ __launch_bounds__(256) void k_gemm2(const half_t* __restrict__ P,
                                               const float* __restrict__ Wp,
                                               const float* __restrict__ Cf,
                                               half_t* __restrict__ outp, int n) {
    constexpr int COLS = FOUT / 4;
    int lane = threadIdx.x & 63;
    int part = __builtin_amdgcn_readfirstlane(threadIdx.x >> 6);
    int node = blockIdx.x * 64 + lane;
    if (node >= n) return;

    half8 xr[FIN / 8];
    const half8* p8 = (const half8*)(P + (size_t)node * FIN);
#pragma unroll
    for (int i = 0; i < FIN / 8; ++i) xr[i] = p8[i];
    const half_t* x = (const half_t*)xr;

    const float* wq = Wp + part * COLS;
    const float* cq = Cf + part * COLS;

#pragma unroll 1
    for (int c0 = 0; c0 < COLS; c0 += 16) {
        float4 a0 = make_float4(0, 0, 0, 0), a1 = a0, a2 = a0, a3 = a0;
        const float* wbase = wq + c0;
#pragma unroll
        for (int k = 0; k < FIN; ++k) {
            float xv = (float)x[k];
            const float4* wr = (const float4*)(wbase + k * FOUT);
            float4 w0 = wr[0], w1 = wr[1], w2 = wr[2], w3 = wr[3];
            a0.x = fmaf(xv, w0.x, a0.x); a0.y = fmaf(xv, w0.y, a0.y);
            a0.z = fmaf(xv, w0.z, a0.z); a0.w = fmaf(xv, w0.w, a0.w);
            a1.x = fmaf(xv, w1.x, a1.x); a1.y = fmaf(xv, w1.y, a1.y);
            a1.z = fmaf(xv, w1.z, a1.z); a1.w = fmaf(xv, w1.w, a1.w);
            a2.x = fmaf(xv, w2.x, a2.x); a2.y = fmaf(xv, w2.y, a2.y);
            a2.z = fmaf(xv, w2.z, a2.z); a2.w = fmaf(xv, w2.w, a2.w);
            a3.x = fmaf(xv, w3.x, a3.x); a3.y = fmaf(xv, w3.y, a3.y);
            a3.z = fmaf(xv, w3.z, a3.z); a3.w = fmaf(xv, w3.w, a3.w);
        }
        const float4* c4 = (const float4*)(cq + c0);
        float4 cA = c4[0], cB = c4[1], cC = c4[2], cD = c4[3];
        half8 h0, h1;
        h0[0] = (half_t)fmaxf(a0.x + cA.x, 0.0f); h0[1] = (half_t)fmaxf(a0.y + cA.y, 0.0f);
        h0[2] = (half_t)fmaxf(a0.z + cA.z, 0.0f); h0[3] = (half_t)fmaxf(a0.w + cA.w, 0.0f);
        h0[4] = (half_t)fmaxf(a1.x + cB.x, 0.0f); h0[5] = (half_t)fmaxf(a1.y + cB.y, 0.0f);
        h0[6] = (half_t)fmaxf(a1.z + cB.z, 0.0f); h0[7] = (half_t)fmaxf(a1.w + cB.w, 0.0f);
        h1[0] = (half_t)fmaxf(a2.x + cC.x, 0.0f); h1[1] = (half_t)fmaxf(a2.y + cC.y, 0.0f);
        h1[2] = (half_t)fmaxf(a2.z + cC.z, 0.0f); h1[3] = (half_t)fmaxf(a2.w + cC.w, 0.0f);
        h1[4] = (half_t)fmaxf(a3.x + cD.x, 0.0f); h1[5] = (half_t)fmaxf(a3.y + cD.y, 0.0f);
        h1[6] = (half_t)fmaxf(a3.z + cD.z, 0.0f); h1[7] = (half_t)fmaxf(a3.w + cD.w, 0.0f);
        half8* oh = (half8*)(outp + (size_t)node * FOUT + part * COLS + c0);
        oh[0] = h0;
        oh[1] = h1;
    }
}

// ================= pool (fp16 input; batch sorted, flush-on-change) =================

__global__ void k_pool(const half_t* __restrict__ H, const int* __restrict__ batch,
                       float* __restrict__ sums, int n) {
    int f = threadIdx.x;            // 0..127
    int base = blockIdx.x * 32;
    if (base >= n) return;
    int endn = min(base + 32, n);
    int cur = batch[base];
    float acc = 0.0f;
    for (int node = base; node < endn; ++node) {
        int bb = batch[node];
        if (bb != cur) { atomicAdd(&sums[cur * 128 + f], acc); acc = 0.0f; cur = bb; }
        acc += (float)H[(size_t)node * 128 + f];
    }
    atomicAdd(&sums[cur * 128 + f], acc);
}

__global__ void k_pool_div(const float* __restrict__ sums, const int* __restrict__ batch,
                           float* __restrict__ out, int n, int nB) {
    int i = blockIdx.x * blockDim.x + threadIdx.x;
    if (i >= nB * 128) return;
    int b = i >> 7;
    int lo = 0, hi = n;
    while (lo < hi) { int mid = (lo + hi) >> 1; if (batch[mid] < b) lo = mid + 1; else hi = mid; }
    int start = lo;
    lo = 0; hi = n;
    while (lo < hi) { int mid = (lo + hi) >> 1; if (batch[mid] < b + 1) lo = mid + 1; else hi = mid; }
    float cnt = (float)(lo - start);
    out[i] = sums[i] / fmaxf(cnt, 1.0f);
}

// ================= launch =================

extern "C" void kernel_launch(void* const* d_in, const int* in_sizes, int n_in,
                              void* d_out, int out_size, void* d_ws, size_t ws_size,
                              hipStream_t stream) {
    const float* x   = (const float*)d_in[0];
    const int*   ei  = (const int*)d_in[1];
    const int*   bat = (const int*)d_in[2];
    const float* W1  = (const float*)d_in[3];
    const float* b1  = (const float*)d_in[4];
    const float* W2  = (const float*)d_in[5];
    const float* b2  = (const float*)d_in[6];
    const float* W3  = (const float*)d_in[7];
    const float* b3  = (const float*)d_in[8];
    const float* g1  = (const float*)d_in[9];
    const float* be1 = (const float*)d_in[10];
    const float* m1  = (const float*)d_in[11];
    const float* v1  = (const float*)d_in[12];
    const float* g2  = (const float*)d_in[13];
    const float* be2 = (const float*)d_in[14];
    const float* m2  = (const float*)d_in[15];
    const float* v2  = (const float*)d_in[16];

    const int N = in_sizes[0] / 22;
    const int E = in_sizes[1] / 2;
    const int B = out_size / 128;
    const int* src = ei;
    const int* dst = ei + E;

    const int nblk = (E + EPB - 1) / EPB;
    const int NBKT = (N + 511) >> 9;

    size_t off = 0;
    char* base = (char*)d_ws;
    auto alloc = [&](size_t bytes) -> void* {
        void* p = base + off;
        off = (off + bytes + 255) & ~(size_t)255;
        return p;
    };
    int*    rowptr = (int*)alloc((size_t)(N + 1) * 4);
    int*    countsT = (int*)alloc((size_t)nblk * 256 * 4);
    int*    colSum = (int*)alloc(256 * 4);
    int*    bucketBase = (int*)alloc(257 * 4);
    u32*    rec    = (u32*)alloc((size_t)E * 4);
    float*  dis    = (float*)alloc((size_t)N * 4);
    float*  dinv   = (float*)alloc((size_t)N * 4);
    u32*    csr    = (u32*)alloc((size_t)E * 4);
    half_t* Xh     = (half_t*)alloc((size_t)N * 24 * 2);
    half_t* Hh1    = (half_t*)alloc((size_t)N * 64 * 2);
    half_t* Hh2    = (half_t*)alloc((size_t)N * 64 * 2);
    half_t* Hh3    = (half_t*)alloc((size_t)N * 128 * 2);
    half_t* aggH   = (half_t*)alloc((size_t)N * 64 * 2);
    float*  sums   = (float*)alloc((size_t)B * 128 * 4);
    float*  Wp1    = (float*)alloc(24 * 64 * 4);
    float*  Wp2    = (float*)alloc(64 * 64 * 4);
    float*  Wp3    = (float*)alloc(64 * 128 * 4);
    float*  C1     = (float*)alloc(64 * 4);
    float*  C2     = (float*)alloc(64 * 4);
    float*  C3     = (float*)alloc(128 * 4);

    const int T = 256;
    auto blk = [](long long n, int t) { return (int)((n + t - 1) / t); };

    // ---- weight prep ----
    k_prep_all<<<blk(24 * 64 + 64 * 64 + 64 * 128, T), T, 0, stream>>>(
        W1, b1, g1, be1, m1, v1, W2, b2, g2, be2, m2, v2, W3, b3,
        Wp1, C1, Wp2, C2, Wp3, C3);

    // ---- bucketed CSR build ----
    k_bhist<<<nblk, T, 0, stream>>>(dst, countsT, nblk, E);
    k_colscan<<<256, T, 0, stream>>>(countsT, colSum, nblk);
    k_bscatter<<<nblk, T, 0, stream>>>(src, dst, countsT, colSum, rec, nblk, E);
    k_bbase<<<1, 256, 0, stream>>>(colSum, bucketBase);
    k_bmake1<<<NBKT, T, 0, stream>>>(rec, bucketBase, rowptr, dis, dinv, N);
    k_bfill<<<NBKT, T, 0, stream>>>(rec, bucketBase, rowptr, dis, csr, N);

    // ---- X -> fp16 (padded 24) ----
    k_x2h<<<blk((long long)N * 24, T), T, 0, stream>>>(x, Xh, N);

    // ---- layer 1 ----
    k_gather22h<<<blk(N, 4), T, 0, stream>>>(Xh, rowptr, csr, dinv, aggH, N);
    k_gemm2<24, 64><<<blk(N, 64), T, 0, stream>>>(aggH, Wp1, C1, Hh1, N);

    // ---- layer 2 ----
    k_gather64h<<<blk(N, 8), T, 0, stream>>>(Hh1, rowptr, csr, dinv, aggH, N);
    k_gemm2<64, 64><<<blk(N, 64), T, 0, stream>>>(aggH, Wp2, C2, Hh2, N);

    // ---- layer 3 (unfused; pool separate) ----
    k_gather64h<<<blk(N, 8), T, 0, stream>>>(Hh2, rowptr, csr, dinv, aggH, N);
    k_gemm2<64, 128><<<blk(N, 64), T, 0, stream>>>(aggH, Wp3, C3, Hh3, N);

    // ---- global mean pool ----
    hipMemsetAsync(sums, 0, (size_t)B * 128 * sizeof(float), stream);
    k_pool<<<blk(N, 32), 128, 0, stream>>>(Hh3, bat, sums, N);
    k_pool_div<<<blk(B * 128, T), T, 0, stream>>>(sums, bat, (float*)d_out, N, B);
}

// Round 21
// 333.650 us; speedup vs baseline: 1.0441x; 1.0230x over previous
//
#include <hip/hip_runtime.h>

#define BN_EPS 1e-5f

typedef _Float16 half_t;
typedef _Float16 half4 __attribute__((ext_vector_type(4)));
typedef _Float16 half8 __attribute__((ext_vector_type(8)));
typedef unsigned int u32;
typedef unsigned short u16;

__device__ __forceinline__ float norm_of(u32 w) {
    u16 hb = (u16)(w & 0x7fffu);
    return (float)__builtin_bit_cast(half_t, hb);
}

// ================= bucketed CSR build (bucket = dst >> 9, 512 nodes/bucket) ===========

#define EPB 4096

__global__ void k_bhist(const int* __restrict__ dst, int* __restrict__ countsT,
                        int nblk, int e) {
    __shared__ int h[256];
    h[threadIdx.x] = 0;
    __syncthreads();
    int base = blockIdx.x * EPB;
    int end = min(base + EPB, e);
    for (int i = base + threadIdx.x; i < end; i += 256)
        atomicAdd(&h[dst[i] >> 9], 1);
    __syncthreads();
    countsT[threadIdx.x * nblk + blockIdx.x] = h[threadIdx.x];
}

__global__ void k_colscan(int* __restrict__ countsT, int* __restrict__ colSum, int nblk) {
    __shared__ int lds[256];
    int t = threadIdx.x;
    int* col = countsT + (size_t)blockIdx.x * nblk;
    int carry = 0;
    for (int base = 0; base < nblk; base += 512) {
        int i0 = base + t * 2, i1 = i0 + 1;
        int v0 = (i0 < nblk) ? col[i0] : 0;
        int v1 = (i1 < nblk) ? col[i1] : 0;
        int s = v0 + v1;
        int val = s;
        lds[t] = val;
        __syncthreads();
        for (int off = 1; off < 256; off <<= 1) {
            int tmp = (t >= off) ? lds[t - off] : 0;
            __syncthreads();
            val += tmp;
            lds[t] = val;
            __syncthreads();
        }
        int run = carry + val - s;
        if (i0 < nblk) col[i0] = run;
        if (i1 < nblk) col[i1] = run + v0;
        carry += lds[255];
        __syncthreads();
    }
    if (t == 0) colSum[blockIdx.x] = carry;
}

__global__ void k_bscatter(const int* __restrict__ src, const int* __restrict__ dst,
                           const int* __restrict__ countsT, const int* __restrict__ colSum,
                           u32* __restrict__ rec, int nblk, int e) {
    __shared__ int lds[256];
    __shared__ int cur[256];
    int t = threadIdx.x;
    int s = colSum[t];
    int val = s;
    lds[t] = val;
    __syncthreads();
    for (int off = 1; off < 256; off <<= 1) {
        int tmp = (t >= off) ? lds[t - off] : 0;
        __syncthreads();
        val += tmp;
        lds[t] = val;
        __syncthreads();
    }
    int basev = val - s;
    cur[t] = countsT[t * nblk + blockIdx.x] + basev;
    __syncthreads();
    int base = blockIdx.x * EPB;
    int end = min(base + EPB, e);
    for (int i = base + t; i < end; i += 256) {
        int d = dst[i], sv = src[i];
        int pos = atomicAdd(&cur[d >> 9], 1);
        rec[pos] = ((u32)sv << 9) | (u32)(d & 511);
    }
}

// Per-bucket: bucket bounds from colSum scan; histogram + LDS scan -> rowptr, dis, dinv
__global__ void k_bmake1(const u32* __restrict__ rec, const int* __restrict__ colSum,
                         int* __restrict__ rowptr, float* __restrict__ dis,
                         float* __restrict__ dinv, int n) {
    __shared__ int h[512];
    __shared__ int ps[256];
    int t = threadIdx.x;
    // bucket bounds via in-LDS inclusive scan of colSum
    int cs = colSum[t];
    int val = cs;
    ps[t] = val;
    __syncthreads();
    for (int off = 1; off < 256; off <<= 1) {
        int tmp = (t >= off) ? ps[t - off] : 0;
        __syncthreads();
        val += tmp;
        ps[t] = val;
        __syncthreads();
    }
    int beg = (blockIdx.x == 0) ? 0 : ps[blockIdx.x - 1];
    int end = ps[blockIdx.x];
    __syncthreads();
    h[t] = 0; h[t + 256] = 0;
    __syncthreads();
    for (int i = beg + t; i < end; i += 256)
        atomicAdd(&h[rec[i] & 511], 1);
    __syncthreads();
    int node0 = blockIdx.x << 9;
    int d0 = h[2 * t], d1 = h[2 * t + 1];
    int pair = d0 + d1;
    ps[t] = pair;
    __syncthreads();
    int val2 = pair;
    for (int off = 1; off < 256; off <<= 1) {
        int tmp = (t >= off) ? ps[t - off] : 0;
        __syncthreads();
        val2 += tmp;
        ps[t] = val2;
        __syncthreads();
    }
    int excl0 = beg + val2 - pair;
    int nodeA = node0 + 2 * t, nodeB = nodeA + 1;
    if (nodeA <= n) rowptr[nodeA] = excl0;
    if (nodeB <= n) rowptr[nodeB] = excl0 + d0;
    if (nodeA < n) { float dd = (float)(d0 + 1); dis[nodeA] = rsqrtf(dd); dinv[nodeA] = 1.0f / dd; }
    if (nodeB < n) { float dd = (float)(d1 + 1); dis[nodeB] = rsqrtf(dd); dinv[nodeB] = 1.0f / dd; }
    if ((n & 511) == 0 && blockIdx.x == gridDim.x - 1 && t == 255) rowptr[n] = end;
}

__global__ void k_bfill(const u32* __restrict__ rec, const int* __restrict__ colSum,
                        const int* __restrict__ rowptr, const float* __restrict__ dis,
                        u32* __restrict__ csr, int n) {
    __shared__ int ps[256];
    __shared__ int cur[512];
    __shared__ float disl[512];
    int t = threadIdx.x;
    int cs = colSum[t];
    int val = cs;
    ps[t] = val;
    __syncthreads();
    for (int off = 1; off < 256; off <<= 1) {
        int tmp = (t >= off) ? ps[t - off] : 0;
        __syncthreads();
        val += tmp;
        ps[t] = val;
        __syncthreads();
    }
    int beg = (blockIdx.x == 0) ? 0 : ps[blockIdx.x - 1];
    int end = ps[blockIdx.x];
    __syncthreads();
    int node0 = blockIdx.x << 9;
    for (int j = t; j < 512; j += 256) {
        int node = node0 + j;
        cur[j]  = (node < n) ? rowptr[node] : 0;
        disl[j] = (node < n) ? dis[node] : 0.0f;
    }
    __syncthreads();
    for (int i = beg + t; i < end; i += 256) {
        u32 r = rec[i];
        int dl = r & 511;
        int s = (int)(r >> 9);
        int pos = atomicAdd(&cur[dl], 1);
        half_t hh = (half_t)(dis[s] * disl[dl]);
        csr[pos] = ((u32)s << 15) | (u32)__builtin_bit_cast(u16, hh);
    }
}

// ================= X -> fp16 padded 24-wide =================

__global__ void k_x2h(const float* __restrict__ X, half_t* __restrict__ Xh, int n) {
    int i = blockIdx.x * blockDim.x + threadIdx.x;
    if (i >= n * 24) return;
    int node = i / 24, c = i % 24;
    Xh[i] = (c < 22) ? (half_t)X[(size_t)node * 22 + c] : (half_t)0.0f;
}

// ================= gather-aggregate (fp16 features, fp32 accumulate, fp16 out) ========

__global__ void k_gather22h(const half_t* __restrict__ Xh, const int* __restrict__ rowptr,
                            const u32* __restrict__ csr, const float* __restrict__ dinv,
                            half_t* __restrict__ out, int n) {
    int node = blockIdx.x * 4 + (threadIdx.x >> 6);
    if (node >= n) return;
    int lane = threadIdx.x & 63;
    int esub = lane >> 3;        // 0..7
    int sub  = lane & 7;         // 0..7
    bool act = sub < 6;
    const half4* X4 = (const half4*)Xh;   // 6 half4 per node
    int beg = rowptr[node], end = rowptr[node + 1];
    float4 a0 = make_float4(0, 0, 0, 0), a1 = a0;
    for (int e = beg; e < end; e += 16) {
        int i0 = e + esub, i1 = e + 8 + esub;
        u32 w0 = csr[min(i0, end - 1)];
        u32 w1 = csr[min(i1, end - 1)];
        if (act && i0 < end) {
            float nn = norm_of(w0);
            half4 h = X4[(size_t)(w0 >> 15) * 6 + sub];
            a0.x = fmaf((float)h.x, nn, a0.x); a0.y = fmaf((float)h.y, nn, a0.y);
            a0.z = fmaf((float)h.z, nn, a0.z); a0.w = fmaf((float)h.w, nn, a0.w);
        }
        if (act && i1 < end) {
            float nn = norm_of(w1);
            half4 h = X4[(size_t)(w1 >> 15) * 6 + sub];
            a1.x = fmaf((float)h.x, nn, a1.x); a1.y = fmaf((float)h.y, nn, a1.y);
            a1.z = fmaf((float)h.z, nn, a1.z); a1.w = fmaf((float)h.w, nn, a1.w);
        }
    }
    float4 a;
    a.x = a0.x + a1.x; a.y = a0.y + a1.y; a.z = a0.z + a1.z; a.w = a0.w + a1.w;
#pragma unroll
    for (int d = 8; d <= 32; d <<= 1) {
        a.x += __shfl_xor(a.x, d); a.y += __shfl_xor(a.y, d);
        a.z += __shfl_xor(a.z, d); a.w += __shfl_xor(a.w, d);
    }
    if (esub == 0 && act) {
        float di = dinv[node];
        half4 hs = X4[(size_t)node * 6 + sub];
        half4 r;
        r.x = (half_t)fmaf((float)hs.x, di, a.x);
        r.y = (half_t)fmaf((float)hs.y, di, a.y);
        r.z = (half_t)fmaf((float)hs.z, di, a.z);
        r.w = (half_t)fmaf((float)hs.w, di, a.w);
        ((half4*)out)[(size_t)node * 6 + sub] = r;
    }
}

// 64-wide: HALF-WAVE per node; lane = nodeSub(2) x esub(4) x sub(8); half8 loads
__global__ void k_gather64h(const half_t* __restrict__ H, const int* __restrict__ rowptr,
                            const u32* __restrict__ csr, const float* __restrict__ dinv,
                            half_t* __restrict__ out, int n) {
    int lane = threadIdx.x & 63;
    int nsub = lane >> 5;        // 0..1 (half-wave)
    int hl   = lane & 31;
    int esub = hl >> 3;          // 0..3
    int sub  = hl & 7;           // 0..7
    int node = blockIdx.x * 8 + (int)(threadIdx.x >> 6) * 2 + nsub;
    if (node >= n) return;
    const half8* H8 = (const half8*)H;    // 8 half8 per node
    int beg = rowptr[node], end = rowptr[node + 1];
    float a0[8], a1[8];
#pragma unroll
    for (int j = 0; j < 8; ++j) { a0[j] = 0.0f; a1[j] = 0.0f; }
    for (int e = beg; e < end; e += 8) {
        int i0 = e + esub, i1 = e + 4 + esub;
        u32 w0 = csr[min(i0, end - 1)];
        u32 w1 = csr[min(i1, end - 1)];
        if (i0 < end) {
            float nn = norm_of(w0);
            half8 h = H8[(size_t)(w0 >> 15) * 8 + sub];
#pragma unroll
            for (int j = 0; j < 8; ++j) a0[j] = fmaf((float)h[j], nn, a0[j]);
        }
        if (i1 < end) {
            float nn = norm_of(w1);
            half8 h = H8[(size_t)(w1 >> 15) * 8 + sub];
#pragma unroll
            for (int j = 0; j < 8; ++j) a1[j] = fmaf((float)h[j], nn, a1[j]);
        }
    }
    float acc[8];
#pragma unroll
    for (int j = 0; j < 8; ++j) acc[j] = a0[j] + a1[j];
#pragma unroll
    for (int d = 8; d <= 16; d <<= 1) {
#pragma unroll
        for (int j = 0; j < 8; ++j) acc[j] += __shfl_xor(acc[j], d);
    }
    if (esub == 0) {
        float di = dinv[node];
        half8 hs = H8[(size_t)node * 8 + sub];
        half8 r;
#pragma unroll
        for (int j = 0; j < 8; ++j) r[j] = (half_t)fmaf((float)hs[j], di, acc[j]);
        ((half8*)out)[(size_t)node * 8 + sub] = r;
    }
}

// ================= weight prep =================

__global__ void k_prep_all(const float* __restrict__ W1, const float* __restrict__ b1,
                           const float* __restrict__ g1, const float* __restrict__ be1,
                           const float* __restrict__ m1, const float* __restrict__ v1,
                           const float* __restrict__ W2, const float* __restrict__ b2,
                           const float* __restrict__ g2, const float* __restrict__ be2,
                           const float* __restrict__ m2, const float* __restrict__ v2,
                           const float* __restrict__ W3, const float* __restrict__ b3,
                           float* __restrict__ Wp1, float* __restrict__ C1,
                           float* __restrict__ Wp2, float* __restrict__ C2,
                           float* __restrict__ Wp3, float* __restrict__ C3) {
    int i = blockIdx.x * blockDim.x + threadIdx.x;
    if (i < 24 * 64) {
        int r = i / 64, c = i % 64;
        float A = g1[c] * rsqrtf(v1[c] + BN_EPS);
        Wp1[i] = (r < 22) ? W1[r * 64 + c] * A : 0.0f;
        if (i < 64) C1[i] = be1[i] + (b1[i] - m1[i]) * A;
    }
    int j = i - 24 * 64;
    if (j >= 0 && j < 64 * 64) {
        int c = j % 64;
        float A = g2[c] * rsqrtf(v2[c] + BN_EPS);
        Wp2[j] = W2[j] * A;
        if (j < 64) C2[j] = be2[j] + (b2[j] - m2[j]) * A;
    }
    int k = i - 24 * 64 - 64 * 64;
    if (k >= 0 && k < 64 * 128) {
        Wp3[k] = W3[k];
        if (k < 128) C3[k] = b3[k];
    }
}

// ================= GEMM (layers 1,2): fp16 in/out; wave-split columns =================

template <int FIN, int FOUT>
__global__ __launch_bounds__(256) void k_gemm2(const half_t* __restrict__ P,
                                               const float* __restrict__ Wp,
                                               const float* __restrict__ Cf,
                                               half_t* __restrict__ outp, int n) {
    constexpr int COLS = FOUT / 4;
    int lane = threadIdx.x & 63;
    int part = __builtin_amdgcn_readfirstlane(threadIdx.x >> 6);
    int node = blockIdx.x * 64 + lane;
    if (node >= n) return;

    half8 xr[FIN / 8];
    const half8* p8 = (const half8*)(P + (size_t)node * FIN);
#pragma unroll
    for (int i = 0; i < FIN / 8; ++i) xr[i] = p8[i];
    const half_t* x = (const half_t*)xr;

    const float* wq = Wp + part * COLS;
    const float* cq = Cf + part * COLS;

#pragma unroll 1
    for (int c0 = 0; c0 < COLS; c0 += 16) {
        float4 a0 = make_float4(0, 0, 0, 0), a1 = a0, a2 = a0, a3 = a0;
        const float* wbase = wq + c0;
#pragma unroll
        for (int k = 0; k < FIN; ++k) {
            float xv = (float)x[k];
            const float4* wr = (const float4*)(wbase + k * FOUT);
            float4 w0 = wr[0], w1 = wr[1], w2 = wr[2], w3 = wr[3];
            a0.x = fmaf(xv, w0.x, a0.x); a0.y = fmaf(xv, w0.y, a0.y);
            a0.z = fmaf(xv, w0.z, a0.z); a0.w = fmaf(xv, w0.w, a0.w);
            a1.x = fmaf(xv, w1.x, a1.x); a1.y = fmaf(xv, w1.y, a1.y);
            a1.z = fmaf(xv, w1.z, a1.z); a1.w = fmaf(xv, w1.w, a1.w);
            a2.x = fmaf(xv, w2.x, a2.x); a2.y = fmaf(xv, w2.y, a2.y);
            a2.z = fmaf(xv, w2.z, a2.z); a2.w = fmaf(xv, w2.w, a2.w);
            a3.x = fmaf(xv, w3.x, a3.x); a3.y = fmaf(xv, w3.y, a3.y);
            a3.z = fmaf(xv, w3.z, a3.z); a3.w = fmaf(xv, w3.w, a3.w);
        }
        const float4* c4 = (const float4*)(cq + c0);
        float4 cA = c4[0], cB = c4[1], cC = c4[2], cD = c4[3];
        half8 h0, h1;
        h0[0] = (half_t)fmaxf(a0.x + cA.x, 0.0f); h0[1] = (half_t)fmaxf(a0.y + cA.y, 0.0f);
        h0[2] = (half_t)fmaxf(a0.z + cA.z, 0.0f); h0[3] = (half_t)fmaxf(a0.w + cA.w, 0.0f);
        h0[4] = (half_t)fmaxf(a1.x + cB.x, 0.0f); h0[5] = (half_t)fmaxf(a1.y + cB.y, 0.0f);
        h0[6] = (half_t)fmaxf(a1.z + cB.z, 0.0f); h0[7] = (half_t)fmaxf(a1.w + cB.w, 0.0f);
        h1[0] = (half_t)fmaxf(a2.x + cC.x, 0.0f); h1[1] = (half_t)fmaxf(a2.y + cC.y, 0.0f);
        h1[2] = (half_t)fmaxf(a2.z + cC.z, 0.0f); h1[3] = (half_t)fmaxf(a2.w + cC.w, 0.0f);
        h1[4] = (half_t)fmaxf(a3.x + cD.x, 0.0f); h1[5] = (half_t)fmaxf(a3.y + cD.y, 0.0f);
        h1[6] = (half_t)fmaxf(a3.z + cD.z, 0.0f); h1[7] = (half_t)fmaxf(a3.w + cD.w, 0.0f);
        half8* oh = (half8*)(outp + (size_t)node * FOUT + part * COLS + c0);
        oh[0] = h0;
        oh[1] = h1;
    }
}

// ================= FUSED gemm3 (64->128) + pool via LDS tile (R18 variant) ===========

__global__ __launch_bounds__(256) void k_gemm3pool(const half_t* __restrict__ P,
                                                   const float* __restrict__ Wp,
                                                   const float* __restrict__ Cf,
                                                   const int* __restrict__ batch,
                                                   float* __restrict__ sums, int n) {
    constexpr int FIN = 64, FOUT = 128, COLS = 32;
    __shared__ half_t tile[128][66];
    __shared__ int batl[64];
    int lane = threadIdx.x & 63;
    int part = __builtin_amdgcn_readfirstlane(threadIdx.x >> 6);
    int node = blockIdx.x * 64 + lane;
    bool valid = node < n;

    if (threadIdx.x < 64) {
        int nd = blockIdx.x * 64 + threadIdx.x;
        batl[threadIdx.x] = (nd < n) ? batch[nd] : -1;
    }

    half8 xr[FIN / 8];
    if (valid) {
        const half8* p8 = (const half8*)(P + (size_t)node * FIN);
#pragma unroll
        for (int i = 0; i < FIN / 8; ++i) xr[i] = p8[i];
    } else {
#pragma unroll
        for (int i = 0; i < FIN / 8; ++i) xr[i] = half8{};
    }
    const half_t* x = (const half_t*)xr;
    const float* wq = Wp + part * COLS;
    const float* cq = Cf + part * COLS;

#pragma unroll 1
    for (int c0 = 0; c0 < COLS; c0 += 16) {
        float4 a0 = make_float4(0, 0, 0, 0), a1 = a0, a2 = a0, a3 = a0;
        const float* wbase = wq + c0;
#pragma unroll
        for (int k = 0; k < FIN; ++k) {
            float xv = (float)x[k];
            const float4* wr = (const float4*)(wbase + k * FOUT);
            float4 w0 = wr[0], w1 = wr[1], w2 = wr[2], w3 = wr[3];
            a0.x = fmaf(xv, w0.x, a0.x); a0.y = fmaf(xv, w0.y, a0.y);
            a0.z = fmaf(xv, w0.z, a0.z); a0.w = fmaf(xv, w0.w, a0.w);
            a1.x = fmaf(xv, w1.x, a1.x); a1.y = fmaf(xv, w1.y, a1.y);
            a1.z = fmaf(xv, w1.z, a1.z); a1.w = fmaf(xv, w1.w, a1.w);
            a2.x = fmaf(xv, w2.x, a2.x); a2.y = fmaf(xv, w2.y, a2.y);
            a2.z = fmaf(xv, w2.z, a2.z); a2.w = fmaf(xv, w2.w, a2.w);
            a3.x = fmaf(xv, w3.x, a3.x); a3.y = fmaf(xv, w3.y, a3.y);
            a3.z = fmaf(xv, w3.z, a3.z); a3.w = fmaf(xv, w3.w, a3.w);
        }
        const float4* c4 = (const float4*)(cq + c0);
        float4 cA = c4[0], cB = c4[1], cC = c4[2], cD = c4[3];
        int r0 = part * COLS + c0;
        tile[r0 +  0][lane] = (half_t)fmaxf(a0.x + cA.x, 0.0f);
        tile[r0 +  1][lane] = (half_t)fmaxf(a0.y + cA.y, 0.0f);
        tile[r0 +  2][lane] = (half_t)fmaxf(a0.z + cA.z, 0.0f);
        tile[r0 +  3][lane] = (half_t)fmaxf(a0.w + cA.w, 0.0f);
        tile[r0 +  4][lane] = (half_t)fmaxf(a1.x + cB.x, 0.0f);
        tile[r0 +  5][lane] = (half_t)fmaxf(a1.y + cB.y, 0.0f);
        tile[r0 +  6][lane] = (half_t)fmaxf(a1.z + cB.z, 0.0f);
        tile[r0 +  7][lane] = (half_t)fmaxf(a1.w + cB.w, 0.0f);
        tile[r0 +  8][lane] = (half_t)fmaxf(a2.x + cC.x, 0.0f);
        tile[r0 +  9][lane] = (half_t)fmaxf(a2.y + cC.y, 0.0f);
        tile[r0 + 10][lane] = (half_t)fmaxf(a2.z + cC.z, 0.0f);
        tile[r0 + 11][lane] = (half_t)fmaxf(a2.w + cC.w, 0.0f);
        tile[r0 + 12][lane] = (half_t)fmaxf(a3.x + cD.x, 0.0f);
        tile[r0 + 13][lane] = (half_t)fmaxf(a3.y + cD.y, 0.0f);
        tile[r0 + 14][lane] = (half_t)fmaxf(a3.z + cD.z, 0.0f);
        tile[r0 + 15][lane] = (half_t)fmaxf(a3.w + cD.w, 0.0f);
    }
    __syncthreads();
    if (threadIdx.x < 128) {
        int col = threadIdx.x;
        int cur = batl[0];
        float acc = 0.0f;
        for (int i = 0; i < 64; ++i) {
            int b = batl[i];
            if (b < 0) break;
            if (b != cur) { atomicAdd(&sums[cur * 128 + col], acc); acc = 0.0f; cur = b; }
            acc += (float)tile[col][i];
        }
        if (cur >= 0) atomicAdd(&sums[cur * 128 + col], acc);
    }
}

__global__ void k_pool_div(const float* __restrict__ sums, const int* __restrict__ batch,
                           float* __restrict__ out, int n, int nB) {
    int i = blockIdx.x * blockDim.x + threadIdx.x;
    if (i >= nB * 128) return;
    int b = i >> 7;
    int lo = 0, hi = n;
    while (lo < hi) { int mid = (lo + hi) >> 1; if (batch[mid] < b) lo = mid + 1; else hi = mid; }
    int start = lo;
    lo = 0; hi = n;
    while (lo < hi) { int mid = (lo + hi) >> 1; if (batch[mid] < b + 1) lo = mid + 1; else hi = mid; }
    float cnt = (float)(lo - start);
    out[i] = sums[i] / fmaxf(cnt, 1.0f);
}

// ================= launch =================

extern "C" void kernel_launch(void* const* d_in, const int* in_sizes, int n_in,
                              void* d_out, int out_size, void* d_ws, size_t ws_size,
                              hipStream_t stream) {
    const float* x   = (const float*)d_in[0];
    const int*   ei  = (const int*)d_in[1];
    const int*   bat = (const int*)d_in[2];
    const float* W1  = (const float*)d_in[3];
    const float* b1  = (const float*)d_in[4];
    const float* W2  = (const float*)d_in[5];
    const float* b2  = (const float*)d_in[6];
    const float* W3  = (const float*)d_in[7];
    const float* b3  = (const float*)d_in[8];
    const float* g1  = (const float*)d_in[9];
    const float* be1 = (const float*)d_in[10];
    const float* m1  = (const float*)d_in[11];
    const float* v1  = (const float*)d_in[12];
    const float* g2  = (const float*)d_in[13];
    const float* be2 = (const float*)d_in[14];
    const float* m2  = (const float*)d_in[15];
    const float* v2  = (const float*)d_in[16];

    const int N = in_sizes[0] / 22;
    const int E = in_sizes[1] / 2;
    const int B = out_size / 128;
    const int* src = ei;
    const int* dst = ei + E;

    const int nblk = (E + EPB - 1) / EPB;
    const int NBKT = (N + 511) >> 9;

    size_t off = 0;
    char* base = (char*)d_ws;
    auto alloc = [&](size_t bytes) -> void* {
        void* p = base + off;
        off = (off + bytes + 255) & ~(size_t)255;
        return p;
    };
    int*    rowptr = (int*)alloc((size_t)(N + 1) * 4);
    int*    countsT = (int*)alloc((size_t)nblk * 256 * 4);
    int*    colSum = (int*)alloc(256 * 4);
    u32*    rec    = (u32*)alloc((size_t)E * 4);
    float*  dis    = (float*)alloc((size_t)N * 4);
    float*  dinv   = (float*)alloc((size_t)N * 4);
    u32*    csr    = (u32*)alloc((size_t)E * 4);
    half_t* Xh     = (half_t*)alloc((size_t)N * 24 * 2);
    half_t* Hh1    = (half_t*)alloc((size_t)N * 64 * 2);
    half_t* Hh2    = (half_t*)alloc((size_t)N * 64 * 2);
    half_t* aggH   = (half_t*)alloc((size_t)N * 64 * 2);
    float*  sums   = (float*)alloc((size_t)B * 128 * 4);
    float*  Wp1    = (float*)alloc(24 * 64 * 4);
    float*  Wp2    = (float*)alloc(64 * 64 * 4);
    float*  Wp3    = (float*)alloc(64 * 128 * 4);
    float*  C1     = (float*)alloc(64 * 4);
    float*  C2     = (float*)alloc(64 * 4);
    float*  C3     = (float*)alloc(128 * 4);

    const int T = 256;
    auto blk = [](long long n, int t) { return (int)((n + t - 1) / t); };

    // ---- weight prep ----
    k_prep_all<<<blk(24 * 64 + 64 * 64 + 64 * 128, T), T, 0, stream>>>(
        W1, b1, g1, be1, m1, v1, W2, b2, g2, be2, m2, v2, W3, b3,
        Wp1, C1, Wp2, C2, Wp3, C3);

    // ---- bucketed CSR build ----
    k_bhist<<<nblk, T, 0, stream>>>(dst, countsT, nblk, E);
    k_colscan<<<256, T, 0, stream>>>(countsT, colSum, nblk);
    k_bscatter<<<nblk, T, 0, stream>>>(src, dst, countsT, colSum, rec, nblk, E);
    k_bmake1<<<NBKT, T, 0, stream>>>(rec, colSum, rowptr, dis, dinv, N);
    k_bfill<<<NBKT, T, 0, stream>>>(rec, colSum, rowptr, dis, csr, N);

    // ---- X -> fp16 (padded 24) ----
    k_x2h<<<blk((long long)N * 24, T), T, 0, stream>>>(x, Xh, N);

    // ---- layer 1 ----
    k_gather22h<<<blk(N, 4), T, 0, stream>>>(Xh, rowptr, csr, dinv, aggH, N);
    k_gemm2<24, 64><<<blk(N, 64), T, 0, stream>>>(aggH, Wp1, C1, Hh1, N);

    // ---- layer 2 ----
    k_gather64h<<<blk(N, 8), T, 0, stream>>>(Hh1, rowptr, csr, dinv, aggH, N);
    k_gemm2<64, 64><<<blk(N, 64), T, 0, stream>>>(aggH, Wp2, C2, Hh2, N);

    // ---- layer 3 fused with pool-sum (LDS tile; best-measured variant) ----
    k_gather64h<<<blk(N, 8), T, 0, stream>>>(Hh2, rowptr, csr, dinv, aggH, N);
    hipMemsetAsync(sums, 0, (size_t)B * 128 * sizeof(float), stream);
    k_gemm3pool<<<blk(N, 64), T, 0, stream>>>(aggH, Wp3, C3, bat, sums, N);

    // ---- divide by counts ----
    k_pool_div<<<blk(B * 128, T), T, 0, stream>>>(sums, bat, (float*)d_out, N, B);
}